// Round 1
// baseline (1762.863 us; speedup 1.0000x reference)
//
#include <hip/hip_runtime.h>
#include <math.h>

constexpr int B  = 128;
constexpr int L  = 512;
constexpr int D2 = 512;    // 2H
constexpr int D4 = 1024;   // 4H
constexpr int G3 = 3072;   // 3*4H
constexpr int R3 = 384;    // 3*B (branch-major rows: r = k*B + b)
constexpr float LAMDA = 3.0f;
constexpr float EPSF  = 1e-8f;

// ---------------- init: stack s1,s2,s3 into st3 (384 x 1024) ----------------
__global__ void k_init(const float* __restrict__ s1, const float* __restrict__ s2,
                       const float* __restrict__ s3, float* __restrict__ st3) {
  int idx = blockIdx.x * blockDim.x + threadIdx.x;
  int total = R3 * D4;
  for (; idx < total; idx += gridDim.x * blockDim.x) {
    int r = idx / D4, i = idx - r * D4;
    int k = r / B, b = r - k * B;
    const float* s = (k == 0) ? s1 : (k == 1) ? s2 : s3;
    st3[idx] = s[b * D4 + i];
  }
}

// ---------------- m_norm^2: row sums of squares of (m @ w2 + b2) ----------------
// grid = 65536/64 blocks; each block owns 64 rows, loops all 8 col-tiles -> no atomics
__global__ __launch_bounds__(256) void k_mnorm(const float* __restrict__ m,
                                               const float* __restrict__ w2,
                                               const float* __restrict__ b2,
                                               float* __restrict__ norm2) {
  __shared__ float As[64][33];
  __shared__ float Ws[32][65];
  __shared__ float red[16][64];
  const int tid = threadIdx.x;
  const int ty = tid >> 4, tx = tid & 15;
  const long rowb = (long)blockIdx.x * 64;
  float rowpart[4] = {0.f, 0.f, 0.f, 0.f};
  for (int ct = 0; ct < 8; ++ct) {
    float acc[4][4] = {};
    for (int kc = 0; kc < 16; ++kc) {
#pragma unroll
      for (int i = 0; i < 8; ++i) {
        int li = tid + i * 256;
        int r = li >> 5, c = li & 31;
        As[r][c] = m[(rowb + r) * 512 + kc * 32 + c];
      }
#pragma unroll
      for (int i = 0; i < 8; ++i) {
        int li = tid + i * 256;
        int r = li >> 6, c = li & 63;
        Ws[r][c] = w2[(kc * 32 + r) * 512 + ct * 64 + c];
      }
      __syncthreads();
#pragma unroll
      for (int k = 0; k < 32; ++k) {
        float a[4], bb[4];
#pragma unroll
        for (int i = 0; i < 4; ++i) a[i] = As[ty * 4 + i][k];
#pragma unroll
        for (int j = 0; j < 4; ++j) bb[j] = Ws[k][tx * 4 + j];
#pragma unroll
        for (int i = 0; i < 4; ++i)
#pragma unroll
          for (int j = 0; j < 4; ++j) acc[i][j] = fmaf(a[i], bb[j], acc[i][j]);
      }
      __syncthreads();
    }
#pragma unroll
    for (int j = 0; j < 4; ++j) {
      float bj = b2[ct * 64 + tx * 4 + j];
#pragma unroll
      for (int i = 0; i < 4; ++i) {
        float v = acc[i][j] + bj;
        rowpart[i] = fmaf(v, v, rowpart[i]);
      }
    }
  }
#pragma unroll
  for (int i = 0; i < 4; ++i) red[tx][ty * 4 + i] = rowpart[i];
  __syncthreads();
  if (tid < 64) {
    float s = 0.f;
#pragma unroll
    for (int t = 0; t < 16; ++t) s += red[t][tid];
    norm2[rowb + tid] = s;
  }
}

// ---------------- generic 64x64 tile f32 GEMM: C = act(A@B + bias) ----------------
// BT: B stored [N][K] (transposed access). ACT 0=none 1=relu.
template <bool BT, int ACT>
__global__ __launch_bounds__(256) void k_gemm64(const float* __restrict__ A, int lda,
                                                const float* __restrict__ Bm, int ldb,
                                                const float* __restrict__ bias,
                                                float* __restrict__ C, int ldc, int Kd) {
  __shared__ float As[64][33];
  __shared__ float Bs[32][65];
  const int tid = threadIdx.x;
  const int ty = tid >> 4, tx = tid & 15;
  const int rowb = blockIdx.y * 64;
  const int colb = blockIdx.x * 64;
  float acc[4][4] = {};
  for (int kc = 0; kc < Kd; kc += 32) {
#pragma unroll
    for (int i = 0; i < 8; ++i) {
      int li = tid + i * 256;
      int r = li >> 5, c = li & 31;
      As[r][c] = A[(long)(rowb + r) * lda + kc + c];
    }
    if (!BT) {
#pragma unroll
      for (int i = 0; i < 8; ++i) {
        int li = tid + i * 256;
        int r = li >> 6, c = li & 63;
        Bs[r][c] = Bm[(long)(kc + r) * ldb + colb + c];
      }
    } else {
#pragma unroll
      for (int i = 0; i < 8; ++i) {
        int li = tid + i * 256;
        int n = li >> 5, k = li & 31;
        Bs[k][n] = Bm[(long)(colb + n) * ldb + kc + k];
      }
    }
    __syncthreads();
#pragma unroll
    for (int k = 0; k < 32; ++k) {
      float a[4], bb[4];
#pragma unroll
      for (int i = 0; i < 4; ++i) a[i] = As[ty * 4 + i][k];
#pragma unroll
      for (int j = 0; j < 4; ++j) bb[j] = Bs[k][tx * 4 + j];
#pragma unroll
      for (int i = 0; i < 4; ++i)
#pragma unroll
        for (int j = 0; j < 4; ++j) acc[i][j] = fmaf(a[i], bb[j], acc[i][j]);
    }
    __syncthreads();
  }
#pragma unroll
  for (int i = 0; i < 4; ++i) {
    int row = rowb + ty * 4 + i;
#pragma unroll
    for (int j = 0; j < 4; ++j) {
      int col = colb + tx * 4 + j;
      float v = acc[i][j];
      if (bias) v += bias[col];
      if (ACT == 1) v = fmaxf(v, 0.f);
      C[(long)row * ldc + col] = v;
    }
  }
}

// ---------------- s_norm & c = w2_b . stt per row ----------------
__global__ void k_snorm(const float* __restrict__ stt3, const float* __restrict__ b2,
                        float* __restrict__ sn3, float* __restrict__ c3) {
  int r = blockIdx.x;
  int tid = threadIdx.x;
  float ss = 0.f, sc = 0.f;
  for (int j = tid; j < D2; j += 256) {
    float v = stt3[(long)r * D2 + j];
    ss = fmaf(v, v, ss);
    sc = fmaf(v, b2[j], sc);
  }
  for (int o = 32; o; o >>= 1) {
    ss += __shfl_down(ss, o);
    sc += __shfl_down(sc, o);
  }
  __shared__ float rs[4], rc[4];
  int w = tid >> 6;
  if ((tid & 63) == 0) { rs[w] = ss; rc[w] = sc; }
  __syncthreads();
  if (tid == 0) {
    float S = rs[0] + rs[1] + rs[2] + rs[3];
    float Cc = rc[0] + rc[1] + rc[2] + rc[3];
    sn3[r] = fmaxf(sqrtf(S), EPSF);
    c3[r] = Cc;
  }
}

// ---------------- dot pass: att3[k][b][l] (3 branches fused, one pass over m) ----------------
__global__ __launch_bounds__(256) void k_dot(const float* __restrict__ m,
                                             const float* __restrict__ shat3,
                                             const float* __restrict__ norm2,
                                             const float* __restrict__ sn3,
                                             const float* __restrict__ c3,
                                             const int* __restrict__ mask,
                                             float* __restrict__ att3) {
  __shared__ float sh[3][512];
  int b = blockIdx.x >> 3;
  int lt = blockIdx.x & 7;
  int tid = threadIdx.x;
  for (int k = 0; k < 3; ++k)
    for (int i = tid; i < 512; i += 256) sh[k][i] = shat3[(long)(k * B + b) * D2 + i];
  __syncthreads();
  int j = tid & 3, lidx = tid >> 2;
  int l = lt * 64 + lidx;
  const float4* mrow = reinterpret_cast<const float4*>(m + (long)(b * L + l) * D2);
  float a0 = 0.f, a1 = 0.f, a2 = 0.f;
#pragma unroll 8
  for (int s = 0; s < 32; ++s) {
    int d4 = s * 4 + j;  // float4 index
    float4 mv = mrow[d4];
    const float4 v0 = *reinterpret_cast<const float4*>(&sh[0][d4 * 4]);
    const float4 v1 = *reinterpret_cast<const float4*>(&sh[1][d4 * 4]);
    const float4 v2 = *reinterpret_cast<const float4*>(&sh[2][d4 * 4]);
    a0 += mv.x * v0.x + mv.y * v0.y + mv.z * v0.z + mv.w * v0.w;
    a1 += mv.x * v1.x + mv.y * v1.y + mv.z * v1.z + mv.w * v1.w;
    a2 += mv.x * v2.x + mv.y * v2.y + mv.z * v2.z + mv.w * v2.w;
  }
  a0 += __shfl_xor(a0, 1); a0 += __shfl_xor(a0, 2);
  a1 += __shfl_xor(a1, 1); a1 += __shfl_xor(a1, 2);
  a2 += __shfl_xor(a2, 1); a2 += __shfl_xor(a2, 2);
  if (j == 0) {
    float mn = fmaxf(sqrtf(norm2[b * L + l]), EPSF);
    bool inv = (mask[b * L + l] == 0);
    float acc[3] = {a0, a1, a2};
#pragma unroll
    for (int k = 0; k < 3; ++k) {
      int r = k * B + b;
      float dot = acc[k] + c3[r];
      float att = LAMDA * dot / (mn * sn3[r]);
      att3[(long)r * L + l] = inv ? -INFINITY : att;
    }
  }
}

// ---------------- softmax over L per (k,b) row, in place ----------------
__global__ void k_softmax(float* __restrict__ att3) {
  int r = blockIdx.x;
  float* row = att3 + (long)r * L;
  int tid = threadIdx.x;
  float x0 = row[tid], x1 = row[tid + 256];
  float mx = fmaxf(x0, x1);
  for (int o = 32; o; o >>= 1) mx = fmaxf(mx, __shfl_xor(mx, o));
  __shared__ float rm[4], rs[4];
  int w = tid >> 6;
  if ((tid & 63) == 0) rm[w] = mx;
  __syncthreads();
  mx = fmaxf(fmaxf(rm[0], rm[1]), fmaxf(rm[2], rm[3]));
  float e0 = expf(x0 - mx), e1 = expf(x1 - mx);
  float s = e0 + e1;
  for (int o = 32; o; o >>= 1) s += __shfl_xor(s, o);
  if ((tid & 63) == 0) rs[w] = s;
  __syncthreads();
  s = rs[0] + rs[1] + rs[2] + rs[3];
  float inv = 1.0f / s;
  row[tid] = e0 * inv;
  row[tid + 256] = e1 * inv;
}

// ---------------- f_att = p @ m (3 branches fused, one pass over m) ----------------
__global__ __launch_bounds__(256) void k_fatt(const float* __restrict__ m,
                                              const float* __restrict__ p3,
                                              float* __restrict__ fatt3) {
  __shared__ float pp[3][512];
  __shared__ float red[3][128];
  int b = blockIdx.x >> 2, dt = blockIdx.x & 3;
  int tid = threadIdx.x;
  for (int k = 0; k < 3; ++k)
    for (int i = tid; i < 512; i += 256) pp[k][i] = p3[(long)(k * B + b) * L + i];
  __syncthreads();
  int d = dt * 128 + (tid & 127);
  int half = tid >> 7;
  float a0 = 0.f, a1 = 0.f, a2 = 0.f;
  int l0 = half * 256;
  for (int l = l0; l < l0 + 256; ++l) {
    float mv = m[(long)(b * L + l) * D2 + d];
    a0 = fmaf(pp[0][l], mv, a0);
    a1 = fmaf(pp[1][l], mv, a1);
    a2 = fmaf(pp[2][l], mv, a2);
  }
  int dd = tid & 127;
  if (half == 1) { red[0][dd] = a0; red[1][dd] = a1; red[2][dd] = a2; }
  __syncthreads();
  if (half == 0) {
    fatt3[(long)(0 * B + b) * D2 + d] = a0 + red[0][dd];
    fatt3[(long)(1 * B + b) * D2 + d] = a1 + red[1][dd];
    fatt3[(long)(2 * B + b) * D2 + d] = a2 + red[2][dd];
  }
}

// ---------------- GRU gates: st = (1-z)*n + z*st ----------------
__global__ void k_gates(const float* __restrict__ gx, const float* __restrict__ gh,
                        float* __restrict__ st3) {
  int idx = blockIdx.x * blockDim.x + threadIdx.x;
  if (idx >= R3 * D4) return;
  int r = idx / D4, i = idx - r * D4;
  const float* gxr = gx + (long)r * G3;
  const float* ghr = gh + (long)r * G3;
  float xr = gxr[i], xz = gxr[D4 + i], xn = gxr[2 * D4 + i];
  float hr = ghr[i], hz = ghr[D4 + i], hn = ghr[2 * D4 + i];
  float rr = 1.f / (1.f + expf(-(xr + hr)));
  float zz = 1.f / (1.f + expf(-(xz + hz)));
  float nn = tanhf(xn + rr * hn);
  float h = st3[idx];
  st3[idx] = (1.f - zz) * nn + zz * h;
}

// ---------------- o3[r] = h4[r] . w5 + b5 ----------------
__global__ void k_w5(const float* __restrict__ h4, const float* __restrict__ w5w,
                     const float* __restrict__ w5b, float* __restrict__ o3) {
  int r = blockIdx.x, tid = threadIdx.x;
  float s = 0.f;
  for (int d = tid; d < D4; d += 256) s = fmaf(h4[(long)r * D4 + d], w5w[d], s);
  for (int o = 32; o; o >>= 1) s += __shfl_down(s, o);
  __shared__ float rs[4];
  if ((tid & 63) == 0) rs[tid >> 6] = s;
  __syncthreads();
  if (tid == 0) o3[r] = rs[0] + rs[1] + rs[2] + rs[3] + w5b[0];
}

// ---------------- final log_softmax over 3 branches ----------------
__global__ void k_final(const float* __restrict__ o3, float* __restrict__ out) {
  int b = threadIdx.x;
  if (b >= B) return;
  float v0 = o3[0 * B + b], v1 = o3[1 * B + b], v2 = o3[2 * B + b];
  float mx = fmaxf(v0, fmaxf(v1, v2));
  float s = expf(v0 - mx) + expf(v1 - mx) + expf(v2 - mx);
  float lse = mx + logf(s);
  out[b * 3 + 0] = v0 - lse;
  out[b * 3 + 1] = v1 - lse;
  out[b * 3 + 2] = v2 - lse;
}

extern "C" void kernel_launch(void* const* d_in, const int* in_sizes, int n_in,
                              void* d_out, int out_size, void* d_ws, size_t ws_size,
                              hipStream_t stream) {
  const float* m    = (const float*)d_in[0];
  const float* s1   = (const float*)d_in[1];
  const float* s2   = (const float*)d_in[2];
  const float* s3   = (const float*)d_in[3];
  const int*   mask = (const int*)d_in[4];
  const float* w2w  = (const float*)d_in[5];
  const float* w2b  = (const float*)d_in[6];
  const float* w3w  = (const float*)d_in[7];
  const float* w3b  = (const float*)d_in[8];
  const float* w4w  = (const float*)d_in[9];
  const float* w4b  = (const float*)d_in[10];
  const float* w5w  = (const float*)d_in[11];
  const float* w5b  = (const float*)d_in[12];
  const float* gwi  = (const float*)d_in[13];
  const float* gwh  = (const float*)d_in[14];
  const float* gbi  = (const float*)d_in[15];
  const float* gbh  = (const float*)d_in[16];
  float* out = (float*)d_out;

  float* ws = (float*)d_ws;
  size_t off = 0;
  auto alloc = [&](size_t n) {
    float* p = ws + off;
    off += (n + 63) & ~(size_t)63;
    return p;
  };
  float* norm2 = alloc((size_t)B * L);
  float* st3   = alloc((size_t)R3 * D4);
  float* stt3  = alloc((size_t)R3 * D2);
  float* shat3 = alloc((size_t)R3 * D2);
  float* sn3   = alloc(R3);
  float* c3    = alloc(R3);
  float* att3  = alloc((size_t)3 * B * L);
  float* fatt3 = alloc((size_t)R3 * D2);
  float* gx    = alloc((size_t)R3 * G3);
  float* gh    = alloc((size_t)R3 * G3);
  float* h4    = alloc((size_t)R3 * D4);
  float* o3    = alloc(R3);

  k_init<<<256, 256, 0, stream>>>(s1, s2, s3, st3);
  k_mnorm<<<(B * L) / 64, 256, 0, stream>>>(m, w2w, w2b, norm2);

  for (int hop = 0; hop < 3; ++hop) {
    // stt = st @ w3 + b3   (384x1024 @ 1024x512)
    k_gemm64<false, 0><<<dim3(D2 / 64, R3 / 64), 256, 0, stream>>>(st3, D4, w3w, D2, w3b, stt3, D2, D4);
    k_snorm<<<R3, 256, 0, stream>>>(stt3, w2b, sn3, c3);
    // shat = stt @ w2^T    (384x512 @ (512x512)^T)
    k_gemm64<true, 0><<<dim3(D2 / 64, R3 / 64), 256, 0, stream>>>(stt3, D2, w2w, D2, nullptr, shat3, D2, D2);
    k_dot<<<B * 8, 256, 0, stream>>>(m, shat3, norm2, sn3, c3, mask, att3);
    k_softmax<<<3 * B, 256, 0, stream>>>(att3);
    k_fatt<<<B * 4, 256, 0, stream>>>(m, att3, fatt3);
    // gx = f_att @ wi^T + bi   (384x512 @ (3072x512)^T)
    k_gemm64<true, 0><<<dim3(G3 / 64, R3 / 64), 256, 0, stream>>>(fatt3, D2, gwi, D2, gbi, gx, G3, D2);
    // gh = st @ wh^T + bh      (384x1024 @ (3072x1024)^T)
    k_gemm64<true, 0><<<dim3(G3 / 64, R3 / 64), 256, 0, stream>>>(st3, D4, gwh, D4, gbh, gh, G3, D4);
    k_gates<<<(R3 * D4) / 256, 256, 0, stream>>>(gx, gh, st3);
  }
  // h = relu(st @ w4 + b4); o = h @ w5 + b5
  k_gemm64<false, 1><<<dim3(D4 / 64, R3 / 64), 256, 0, stream>>>(st3, D4, w4w, D4, w4b, h4, D4, D4);
  k_w5<<<R3, 256, 0, stream>>>(h4, w5w, w5b, o3);
  k_final<<<1, 128, 0, stream>>>(o3, out);
}

// Round 2
// 1091.816 us; speedup vs baseline: 1.6146x; 1.6146x over previous
//
#include <hip/hip_runtime.h>
#include <math.h>

constexpr int B  = 128;
constexpr int L  = 512;
constexpr int D2 = 512;    // 2H
constexpr int D4 = 1024;   // 4H
constexpr int G3 = 3072;   // 3*4H
constexpr int R3 = 384;    // 3*B (branch-major rows: r = k*B + b)
constexpr float LAMDA = 3.0f;
constexpr float EPSF  = 1e-8f;

typedef __attribute__((ext_vector_type(8))) short bf16x8;
typedef __attribute__((ext_vector_type(8))) short short8;
typedef __attribute__((ext_vector_type(4))) float f32x4;

__device__ __forceinline__ ushort f2bf(float v) {
  uint u = __builtin_bit_cast(uint, v);
  u = (u + 0x7fffu + ((u >> 16) & 1u)) >> 16;   // RNE
  return (ushort)u;
}
__device__ __forceinline__ float bflo(uint w) { return __builtin_bit_cast(float, w << 16); }
__device__ __forceinline__ float bfhi(uint w) { return __builtin_bit_cast(float, w & 0xffff0000u); }

// ---------------- init: stack s1,s2,s3 into st3 (384 x 1024) ----------------
__global__ void k_init(const float* __restrict__ s1, const float* __restrict__ s2,
                       const float* __restrict__ s3, float* __restrict__ st3) {
  int idx = blockIdx.x * blockDim.x + threadIdx.x;
  int total = R3 * D4;
  for (; idx < total; idx += gridDim.x * blockDim.x) {
    int r = idx / D4, i = idx - r * D4;
    int k = r / B, b = r - k * B;
    const float* s = (k == 0) ? s1 : (k == 1) ? s2 : s3;
    st3[idx] = s[b * D4 + i];
  }
}

// ---------------- conversions ----------------
__global__ void k_conv_m(const float* __restrict__ m, ushort* __restrict__ mbf) {
  int idx = blockIdx.x * blockDim.x + threadIdx.x;
  const int total8 = (B * L * D2) / 8;
  for (; idx < total8; idx += gridDim.x * blockDim.x) {
    const float4* p = reinterpret_cast<const float4*>(m) + (size_t)idx * 2;
    float4 a = p[0], c = p[1];
    ushort o[8] = {f2bf(a.x), f2bf(a.y), f2bf(a.z), f2bf(a.w),
                   f2bf(c.x), f2bf(c.y), f2bf(c.z), f2bf(c.w)};
    *reinterpret_cast<uint4*>(mbf + (size_t)idx * 8) = *reinterpret_cast<const uint4*>(o);
  }
}

// w2t[n][k] = bf16(w2[k][n])  (512x512)
__global__ void k_w2t(const float* __restrict__ w2, ushort* __restrict__ w2t) {
  __shared__ ushort t[64][65];
  int bk = (blockIdx.x & 7) * 64, bn = (blockIdx.x >> 3) * 64;
  int tid = threadIdx.x;
#pragma unroll
  for (int i = 0; i < 16; ++i) {
    int e = tid + i * 256; int r = e >> 6, c = e & 63;
    t[r][c] = f2bf(w2[(bk + r) * 512 + bn + c]);
  }
  __syncthreads();
#pragma unroll
  for (int i = 0; i < 16; ++i) {
    int e = tid + i * 256; int r = e >> 6, c = e & 63;
    w2t[(bn + r) * 512 + bk + c] = t[c][r];
  }
}

// ---------------- m_norm^2 via bf16 MFMA (never materializes mtt) ----------------
// block: 128 rows, 4 waves x 32 rows; ct loop over 8 col-tiles of 64
__global__ __launch_bounds__(256) void k_mnorm_mfma(const ushort* __restrict__ mbf,
                                                    const ushort* __restrict__ w2t,
                                                    const float* __restrict__ b2,
                                                    float* __restrict__ norm2) {
  __shared__ ushort As[128][40];  // 32 k + 8 pad (80B rows, 16B-aligned)
  __shared__ ushort Bs[64][40];
  const int tid = threadIdx.x;
  const int wv = tid >> 6, ln = tid & 63;
  const int lrow = ln & 15, lk = ln >> 4;
  const long rowb = (long)blockIdx.x * 128;
  float nrm[2][4] = {};
  for (int ct = 0; ct < 8; ++ct) {
    f32x4 acc[2][4] = {};
    for (int kc = 0; kc < 512; kc += 32) {
      {
        int e = tid;
#pragma unroll
        for (int i = 0; i < 2; ++i, e += 256) {
          int r = e >> 2, s = e & 3;
          *reinterpret_cast<short8*>(&As[r][s * 8]) =
              *reinterpret_cast<const short8*>(&mbf[(size_t)(rowb + r) * 512 + kc + s * 8]);
        }
        int r = tid >> 2, s = tid & 3;
        *reinterpret_cast<short8*>(&Bs[r][s * 8]) =
            *reinterpret_cast<const short8*>(&w2t[(size_t)(ct * 64 + r) * 512 + kc + s * 8]);
      }
      __syncthreads();
      bf16x8 af[2], bfr[4];
#pragma unroll
      for (int rf = 0; rf < 2; ++rf)
        af[rf] = *reinterpret_cast<const bf16x8*>(&As[wv * 32 + rf * 16 + lrow][lk * 8]);
#pragma unroll
      for (int cf = 0; cf < 4; ++cf)
        bfr[cf] = *reinterpret_cast<const bf16x8*>(&Bs[cf * 16 + lrow][lk * 8]);
#pragma unroll
      for (int rf = 0; rf < 2; ++rf)
#pragma unroll
        for (int cf = 0; cf < 4; ++cf)
          acc[rf][cf] = __builtin_amdgcn_mfma_f32_16x16x32_bf16(af[rf], bfr[cf], acc[rf][cf], 0, 0, 0);
      __syncthreads();
    }
#pragma unroll
    for (int cf = 0; cf < 4; ++cf) {
      float bb = b2[ct * 64 + cf * 16 + lrow];
#pragma unroll
      for (int rf = 0; rf < 2; ++rf)
#pragma unroll
        for (int j = 0; j < 4; ++j) {
          float v = acc[rf][cf][j] + bb;
          nrm[rf][j] = fmaf(v, v, nrm[rf][j]);
        }
    }
  }
#pragma unroll
  for (int rf = 0; rf < 2; ++rf)
#pragma unroll
    for (int j = 0; j < 4; ++j) {
      float v = nrm[rf][j];
      v += __shfl_xor(v, 1); v += __shfl_xor(v, 2);
      v += __shfl_xor(v, 4); v += __shfl_xor(v, 8);
      nrm[rf][j] = v;
    }
  if (lrow == 0) {
#pragma unroll
    for (int rf = 0; rf < 2; ++rf)
#pragma unroll
      for (int j = 0; j < 4; ++j)
        norm2[rowb + wv * 32 + rf * 16 + lk * 4 + j] = nrm[rf][j];
  }
}

// ---------------- fallback f32 m_norm (kept for small-ws path) ----------------
__global__ __launch_bounds__(256) void k_mnorm(const float* __restrict__ m,
                                               const float* __restrict__ w2,
                                               const float* __restrict__ b2,
                                               float* __restrict__ norm2) {
  __shared__ float As[64][33];
  __shared__ float Ws[32][65];
  __shared__ float red[16][64];
  const int tid = threadIdx.x;
  const int ty = tid >> 4, tx = tid & 15;
  const long rowb = (long)blockIdx.x * 64;
  float rowpart[4] = {0.f, 0.f, 0.f, 0.f};
  for (int ct = 0; ct < 8; ++ct) {
    float acc[4][4] = {};
    for (int kc = 0; kc < 16; ++kc) {
#pragma unroll
      for (int i = 0; i < 8; ++i) {
        int li = tid + i * 256;
        int r = li >> 5, c = li & 31;
        As[r][c] = m[(rowb + r) * 512 + kc * 32 + c];
      }
#pragma unroll
      for (int i = 0; i < 8; ++i) {
        int li = tid + i * 256;
        int r = li >> 6, c = li & 63;
        Ws[r][c] = w2[(kc * 32 + r) * 512 + ct * 64 + c];
      }
      __syncthreads();
#pragma unroll
      for (int k = 0; k < 32; ++k) {
        float a[4], bb[4];
#pragma unroll
        for (int i = 0; i < 4; ++i) a[i] = As[ty * 4 + i][k];
#pragma unroll
        for (int j = 0; j < 4; ++j) bb[j] = Ws[k][tx * 4 + j];
#pragma unroll
        for (int i = 0; i < 4; ++i)
#pragma unroll
          for (int j = 0; j < 4; ++j) acc[i][j] = fmaf(a[i], bb[j], acc[i][j]);
      }
      __syncthreads();
    }
#pragma unroll
    for (int j = 0; j < 4; ++j) {
      float bj = b2[ct * 64 + tx * 4 + j];
#pragma unroll
      for (int i = 0; i < 4; ++i) {
        float v = acc[i][j] + bj;
        rowpart[i] = fmaf(v, v, rowpart[i]);
      }
    }
  }
#pragma unroll
  for (int i = 0; i < 4; ++i) red[tx][ty * 4 + i] = rowpart[i];
  __syncthreads();
  if (tid < 64) {
    float s = 0.f;
#pragma unroll
    for (int t = 0; t < 16; ++t) s += red[t][tid];
    norm2[rowb + tid] = s;
  }
}

// ---------------- generic 64x64 tile f32 GEMM ----------------
template <bool BT, int ACT>
__global__ __launch_bounds__(256) void k_gemm64(const float* __restrict__ A, int lda,
                                                const float* __restrict__ Bm, int ldb,
                                                const float* __restrict__ bias,
                                                float* __restrict__ C, int ldc, int Kd) {
  __shared__ float As[64][33];
  __shared__ float Bs[32][65];
  const int tid = threadIdx.x;
  const int ty = tid >> 4, tx = tid & 15;
  const int rowb = blockIdx.y * 64;
  const int colb = blockIdx.x * 64;
  float acc[4][4] = {};
  for (int kc = 0; kc < Kd; kc += 32) {
#pragma unroll
    for (int i = 0; i < 8; ++i) {
      int li = tid + i * 256;
      int r = li >> 5, c = li & 31;
      As[r][c] = A[(long)(rowb + r) * lda + kc + c];
    }
    if (!BT) {
#pragma unroll
      for (int i = 0; i < 8; ++i) {
        int li = tid + i * 256;
        int r = li >> 6, c = li & 63;
        Bs[r][c] = Bm[(long)(kc + r) * ldb + colb + c];
      }
    } else {
#pragma unroll
      for (int i = 0; i < 8; ++i) {
        int li = tid + i * 256;
        int n = li >> 5, k = li & 31;
        Bs[k][n] = Bm[(long)(colb + n) * ldb + kc + k];
      }
    }
    __syncthreads();
#pragma unroll
    for (int k = 0; k < 32; ++k) {
      float a[4], bb[4];
#pragma unroll
      for (int i = 0; i < 4; ++i) a[i] = As[ty * 4 + i][k];
#pragma unroll
      for (int j = 0; j < 4; ++j) bb[j] = Bs[k][tx * 4 + j];
#pragma unroll
      for (int i = 0; i < 4; ++i)
#pragma unroll
        for (int j = 0; j < 4; ++j) acc[i][j] = fmaf(a[i], bb[j], acc[i][j]);
    }
    __syncthreads();
  }
#pragma unroll
  for (int i = 0; i < 4; ++i) {
    int row = rowb + ty * 4 + i;
#pragma unroll
    for (int j = 0; j < 4; ++j) {
      int col = colb + tx * 4 + j;
      float v = acc[i][j];
      if (bias) v += bias[col];
      if (ACT == 1) v = fmaxf(v, 0.f);
      C[(long)row * ldc + col] = v;
    }
  }
}

// ---------------- s_norm & c = w2_b . stt per row ----------------
__global__ void k_snorm(const float* __restrict__ stt3, const float* __restrict__ b2,
                        float* __restrict__ sn3, float* __restrict__ c3) {
  int r = blockIdx.x;
  int tid = threadIdx.x;
  float ss = 0.f, sc = 0.f;
  for (int j = tid; j < D2; j += 256) {
    float v = stt3[(long)r * D2 + j];
    ss = fmaf(v, v, ss);
    sc = fmaf(v, b2[j], sc);
  }
  for (int o = 32; o; o >>= 1) {
    ss += __shfl_down(ss, o);
    sc += __shfl_down(sc, o);
  }
  __shared__ float rs[4], rc[4];
  int w = tid >> 6;
  if ((tid & 63) == 0) { rs[w] = ss; rc[w] = sc; }
  __syncthreads();
  if (tid == 0) {
    float S = rs[0] + rs[1] + rs[2] + rs[3];
    float Cc = rc[0] + rc[1] + rc[2] + rc[3];
    sn3[r] = fmaxf(sqrtf(S), EPSF);
    c3[r] = Cc;
  }
}

// ---------------- dot pass (bf16 m) ----------------
__global__ __launch_bounds__(256) void k_dot_bf(const ushort* __restrict__ mbf,
                                                const float* __restrict__ shat3,
                                                const float* __restrict__ norm2,
                                                const float* __restrict__ sn3,
                                                const float* __restrict__ c3,
                                                const int* __restrict__ mask,
                                                float* __restrict__ att3) {
  __shared__ float sh[3][512];
  int b = blockIdx.x >> 3;
  int lt = blockIdx.x & 7;
  int tid = threadIdx.x;
  for (int k = 0; k < 3; ++k)
    for (int i = tid; i < 512; i += 256) sh[k][i] = shat3[(long)(k * B + b) * D2 + i];
  __syncthreads();
  int j = tid & 3, lidx = tid >> 2;
  int l = lt * 64 + lidx;
  const uint4* mrow = reinterpret_cast<const uint4*>(mbf + (size_t)(b * L + l) * D2);
  float a0 = 0.f, a1 = 0.f, a2 = 0.f;
#pragma unroll 4
  for (int s = 0; s < 16; ++s) {
    int c = s * 4 + j;
    uint4 mv = mrow[c];
    const float* p0 = &sh[0][c * 8];
    const float* p1 = &sh[1][c * 8];
    const float* p2 = &sh[2][c * 8];
    uint w[4] = {mv.x, mv.y, mv.z, mv.w};
#pragma unroll
    for (int q = 0; q < 4; ++q) {
      float lo = bflo(w[q]), hi = bfhi(w[q]);
      a0 = fmaf(lo, p0[q * 2], a0); a0 = fmaf(hi, p0[q * 2 + 1], a0);
      a1 = fmaf(lo, p1[q * 2], a1); a1 = fmaf(hi, p1[q * 2 + 1], a1);
      a2 = fmaf(lo, p2[q * 2], a2); a2 = fmaf(hi, p2[q * 2 + 1], a2);
    }
  }
  a0 += __shfl_xor(a0, 1); a0 += __shfl_xor(a0, 2);
  a1 += __shfl_xor(a1, 1); a1 += __shfl_xor(a1, 2);
  a2 += __shfl_xor(a2, 1); a2 += __shfl_xor(a2, 2);
  if (j == 0) {
    float mn = fmaxf(sqrtf(norm2[b * L + l]), EPSF);
    bool inv = (mask[b * L + l] == 0);
    float acc[3] = {a0, a1, a2};
#pragma unroll
    for (int k = 0; k < 3; ++k) {
      int r = k * B + b;
      float dot = acc[k] + c3[r];
      float att = LAMDA * dot / (mn * sn3[r]);
      att3[(long)r * L + l] = inv ? -INFINITY : att;
    }
  }
}

// fallback f32 dot
__global__ __launch_bounds__(256) void k_dot(const float* __restrict__ m,
                                             const float* __restrict__ shat3,
                                             const float* __restrict__ norm2,
                                             const float* __restrict__ sn3,
                                             const float* __restrict__ c3,
                                             const int* __restrict__ mask,
                                             float* __restrict__ att3) {
  __shared__ float sh[3][512];
  int b = blockIdx.x >> 3;
  int lt = blockIdx.x & 7;
  int tid = threadIdx.x;
  for (int k = 0; k < 3; ++k)
    for (int i = tid; i < 512; i += 256) sh[k][i] = shat3[(long)(k * B + b) * D2 + i];
  __syncthreads();
  int j = tid & 3, lidx = tid >> 2;
  int l = lt * 64 + lidx;
  const float4* mrow = reinterpret_cast<const float4*>(m + (long)(b * L + l) * D2);
  float a0 = 0.f, a1 = 0.f, a2 = 0.f;
#pragma unroll 8
  for (int s = 0; s < 32; ++s) {
    int d4 = s * 4 + j;
    float4 mv = mrow[d4];
    const float4 v0 = *reinterpret_cast<const float4*>(&sh[0][d4 * 4]);
    const float4 v1 = *reinterpret_cast<const float4*>(&sh[1][d4 * 4]);
    const float4 v2 = *reinterpret_cast<const float4*>(&sh[2][d4 * 4]);
    a0 += mv.x * v0.x + mv.y * v0.y + mv.z * v0.z + mv.w * v0.w;
    a1 += mv.x * v1.x + mv.y * v1.y + mv.z * v1.z + mv.w * v1.w;
    a2 += mv.x * v2.x + mv.y * v2.y + mv.z * v2.z + mv.w * v2.w;
  }
  a0 += __shfl_xor(a0, 1); a0 += __shfl_xor(a0, 2);
  a1 += __shfl_xor(a1, 1); a1 += __shfl_xor(a1, 2);
  a2 += __shfl_xor(a2, 1); a2 += __shfl_xor(a2, 2);
  if (j == 0) {
    float mn = fmaxf(sqrtf(norm2[b * L + l]), EPSF);
    bool inv = (mask[b * L + l] == 0);
    float acc[3] = {a0, a1, a2};
#pragma unroll
    for (int k = 0; k < 3; ++k) {
      int r = k * B + b;
      float dot = acc[k] + c3[r];
      float att = LAMDA * dot / (mn * sn3[r]);
      att3[(long)r * L + l] = inv ? -INFINITY : att;
    }
  }
}

// ---------------- softmax over L per (k,b) row, in place ----------------
__global__ void k_softmax(float* __restrict__ att3) {
  int r = blockIdx.x;
  float* row = att3 + (long)r * L;
  int tid = threadIdx.x;
  float x0 = row[tid], x1 = row[tid + 256];
  float mx = fmaxf(x0, x1);
  for (int o = 32; o; o >>= 1) mx = fmaxf(mx, __shfl_xor(mx, o));
  __shared__ float rm[4], rs[4];
  int w = tid >> 6;
  if ((tid & 63) == 0) rm[w] = mx;
  __syncthreads();
  mx = fmaxf(fmaxf(rm[0], rm[1]), fmaxf(rm[2], rm[3]));
  float e0 = expf(x0 - mx), e1 = expf(x1 - mx);
  float s = e0 + e1;
  for (int o = 32; o; o >>= 1) s += __shfl_xor(s, o);
  if ((tid & 63) == 0) rs[w] = s;
  __syncthreads();
  s = rs[0] + rs[1] + rs[2] + rs[3];
  float inv = 1.0f / s;
  row[tid] = e0 * inv;
  row[tid + 256] = e1 * inv;
}

// ---------------- f_att = p @ m (bf16 m) ----------------
__global__ __launch_bounds__(256) void k_fatt_bf(const ushort* __restrict__ mbf,
                                                 const float* __restrict__ p3,
                                                 float* __restrict__ fatt3) {
  __shared__ float pp[3][512];
  __shared__ float red[3][256];
  int b = blockIdx.x >> 1, dt = blockIdx.x & 1;
  int tid = threadIdx.x;
  for (int k = 0; k < 3; ++k)
    for (int i = tid; i < 512; i += 256) pp[k][i] = p3[(long)(k * B + b) * L + i];
  __syncthreads();
  int dpair = tid & 127, half = tid >> 7;
  int d = dt * 256 + dpair * 2;
  float a[3][2] = {};
  int l0 = half * 256;
  for (int l = l0; l < l0 + 256; ++l) {
    uint w = *reinterpret_cast<const uint*>(&mbf[(size_t)(b * L + l) * D2 + d]);
    float f0 = bflo(w), f1 = bfhi(w);
#pragma unroll
    for (int k = 0; k < 3; ++k) {
      float p = pp[k][l];
      a[k][0] = fmaf(p, f0, a[k][0]);
      a[k][1] = fmaf(p, f1, a[k][1]);
    }
  }
  if (half == 1) {
#pragma unroll
    for (int k = 0; k < 3; ++k) { red[k][dpair * 2] = a[k][0]; red[k][dpair * 2 + 1] = a[k][1]; }
  }
  __syncthreads();
  if (half == 0) {
#pragma unroll
    for (int k = 0; k < 3; ++k) {
      fatt3[(long)(k * B + b) * D2 + d]     = a[k][0] + red[k][dpair * 2];
      fatt3[(long)(k * B + b) * D2 + d + 1] = a[k][1] + red[k][dpair * 2 + 1];
    }
  }
}

// fallback f32 f_att
__global__ __launch_bounds__(256) void k_fatt(const float* __restrict__ m,
                                              const float* __restrict__ p3,
                                              float* __restrict__ fatt3) {
  __shared__ float pp[3][512];
  __shared__ float red[3][128];
  int b = blockIdx.x >> 2, dt = blockIdx.x & 3;
  int tid = threadIdx.x;
  for (int k = 0; k < 3; ++k)
    for (int i = tid; i < 512; i += 256) pp[k][i] = p3[(long)(k * B + b) * L + i];
  __syncthreads();
  int d = dt * 128 + (tid & 127);
  int half = tid >> 7;
  float a0 = 0.f, a1 = 0.f, a2 = 0.f;
  int l0 = half * 256;
  for (int l = l0; l < l0 + 256; ++l) {
    float mv = m[(long)(b * L + l) * D2 + d];
    a0 = fmaf(pp[0][l], mv, a0);
    a1 = fmaf(pp[1][l], mv, a1);
    a2 = fmaf(pp[2][l], mv, a2);
  }
  int dd = tid & 127;
  if (half == 1) { red[0][dd] = a0; red[1][dd] = a1; red[2][dd] = a2; }
  __syncthreads();
  if (half == 0) {
    fatt3[(long)(0 * B + b) * D2 + d] = a0 + red[0][dd];
    fatt3[(long)(1 * B + b) * D2 + d] = a1 + red[1][dd];
    fatt3[(long)(2 * B + b) * D2 + d] = a2 + red[2][dd];
  }
}

// ---------------- GRU gates ----------------
__global__ void k_gates(const float* __restrict__ gx, const float* __restrict__ gh,
                        float* __restrict__ st3) {
  int idx = blockIdx.x * blockDim.x + threadIdx.x;
  if (idx >= R3 * D4) return;
  int r = idx / D4, i = idx - r * D4;
  const float* gxr = gx + (long)r * G3;
  const float* ghr = gh + (long)r * G3;
  float xr = gxr[i], xz = gxr[D4 + i], xn = gxr[2 * D4 + i];
  float hr = ghr[i], hz = ghr[D4 + i], hn = ghr[2 * D4 + i];
  float rr = 1.f / (1.f + expf(-(xr + hr)));
  float zz = 1.f / (1.f + expf(-(xz + hz)));
  float nn = tanhf(xn + rr * hn);
  float h = st3[idx];
  st3[idx] = (1.f - zz) * nn + zz * h;
}

// ---------------- o3[r] = h4[r] . w5 + b5 ----------------
__global__ void k_w5(const float* __restrict__ h4, const float* __restrict__ w5w,
                     const float* __restrict__ w5b, float* __restrict__ o3) {
  int r = blockIdx.x, tid = threadIdx.x;
  float s = 0.f;
  for (int d = tid; d < D4; d += 256) s = fmaf(h4[(long)r * D4 + d], w5w[d], s);
  for (int o = 32; o; o >>= 1) s += __shfl_down(s, o);
  __shared__ float rs[4];
  if ((tid & 63) == 0) rs[tid >> 6] = s;
  __syncthreads();
  if (tid == 0) o3[r] = rs[0] + rs[1] + rs[2] + rs[3] + w5b[0];
}

// ---------------- final log_softmax over 3 branches ----------------
__global__ void k_final(const float* __restrict__ o3, float* __restrict__ out) {
  int b = threadIdx.x;
  if (b >= B) return;
  float v0 = o3[0 * B + b], v1 = o3[1 * B + b], v2 = o3[2 * B + b];
  float mx = fmaxf(v0, fmaxf(v1, v2));
  float s = expf(v0 - mx) + expf(v1 - mx) + expf(v2 - mx);
  float lse = mx + logf(s);
  out[b * 3 + 0] = v0 - lse;
  out[b * 3 + 1] = v1 - lse;
  out[b * 3 + 2] = v2 - lse;
}

extern "C" void kernel_launch(void* const* d_in, const int* in_sizes, int n_in,
                              void* d_out, int out_size, void* d_ws, size_t ws_size,
                              hipStream_t stream) {
  const float* m    = (const float*)d_in[0];
  const float* s1   = (const float*)d_in[1];
  const float* s2   = (const float*)d_in[2];
  const float* s3   = (const float*)d_in[3];
  const int*   mask = (const int*)d_in[4];
  const float* w2w  = (const float*)d_in[5];
  const float* w2b  = (const float*)d_in[6];
  const float* w3w  = (const float*)d_in[7];
  const float* w3b  = (const float*)d_in[8];
  const float* w4w  = (const float*)d_in[9];
  const float* w4b  = (const float*)d_in[10];
  const float* w5w  = (const float*)d_in[11];
  const float* w5b  = (const float*)d_in[12];
  const float* gwi  = (const float*)d_in[13];
  const float* gwh  = (const float*)d_in[14];
  const float* gbi  = (const float*)d_in[15];
  const float* gbh  = (const float*)d_in[16];
  float* out = (float*)d_out;

  float* ws = (float*)d_ws;
  size_t off = 0;
  auto alloc = [&](size_t n) {
    float* p = ws + off;
    off += (n + 63) & ~(size_t)63;
    return p;
  };
  // bf16 buffers first (counted in float units)
  ushort* mbf = (ushort*)alloc((size_t)B * L * D2 / 2);   // 16.78M floats
  ushort* w2t = (ushort*)alloc((size_t)D2 * D2 / 2);
  float* norm2 = alloc((size_t)B * L);
  float* st3   = alloc((size_t)R3 * D4);
  float* stt3  = alloc((size_t)R3 * D2);
  float* shat3 = alloc((size_t)R3 * D2);
  float* sn3   = alloc(R3);
  float* c3    = alloc(R3);
  float* att3  = alloc((size_t)3 * B * L);
  float* fatt3 = alloc((size_t)R3 * D2);
  float* gx    = alloc((size_t)R3 * G3);
  float* gh    = alloc((size_t)R3 * G3);
  float* h4    = alloc((size_t)R3 * D4);
  float* o3    = alloc(R3);
  const bool big = ws_size >= off * sizeof(float);

  k_init<<<256, 256, 0, stream>>>(s1, s2, s3, st3);
  if (big) {
    k_conv_m<<<2048, 256, 0, stream>>>(m, mbf);
    k_w2t<<<64, 256, 0, stream>>>(w2w, w2t);
    k_mnorm_mfma<<<(B * L) / 128, 256, 0, stream>>>(mbf, w2t, w2b, norm2);
  } else {
    k_mnorm<<<(B * L) / 64, 256, 0, stream>>>(m, w2w, w2b, norm2);
  }

  for (int hop = 0; hop < 3; ++hop) {
    k_gemm64<false, 0><<<dim3(D2 / 64, R3 / 64), 256, 0, stream>>>(st3, D4, w3w, D2, w3b, stt3, D2, D4);
    k_snorm<<<R3, 256, 0, stream>>>(stt3, w2b, sn3, c3);
    k_gemm64<true, 0><<<dim3(D2 / 64, R3 / 64), 256, 0, stream>>>(stt3, D2, w2w, D2, nullptr, shat3, D2, D2);
    if (big) {
      k_dot_bf<<<B * 8, 256, 0, stream>>>(mbf, shat3, norm2, sn3, c3, mask, att3);
    } else {
      k_dot<<<B * 8, 256, 0, stream>>>(m, shat3, norm2, sn3, c3, mask, att3);
    }
    k_softmax<<<3 * B, 256, 0, stream>>>(att3);
    if (big) {
      k_fatt_bf<<<B * 2, 256, 0, stream>>>(mbf, att3, fatt3);
    } else {
      k_fatt<<<B * 4, 256, 0, stream>>>(m, att3, fatt3);
    }
    k_gemm64<true, 0><<<dim3(G3 / 64, R3 / 64), 256, 0, stream>>>(fatt3, D2, gwi, D2, gbi, gx, G3, D2);
    k_gemm64<true, 0><<<dim3(G3 / 64, R3 / 64), 256, 0, stream>>>(st3, D4, gwh, D4, gbh, gh, G3, D4);
    k_gates<<<(R3 * D4) / 256, 256, 0, stream>>>(gx, gh, st3);
  }
  k_gemm64<false, 1><<<dim3(D4 / 64, R3 / 64), 256, 0, stream>>>(st3, D4, w4w, D4, w4b, h4, D4, D4);
  k_w5<<<R3, 256, 0, stream>>>(h4, w5w, w5b, o3);
  k_final<<<1, 128, 0, stream>>>(o3, out);
}

// Round 3
// 653.956 us; speedup vs baseline: 2.6957x; 1.6696x over previous
//
#include <hip/hip_runtime.h>
#include <math.h>

constexpr int B  = 128;
constexpr int L  = 512;
constexpr int D2 = 512;    // 2H
constexpr int D4 = 1024;   // 4H
constexpr int G3 = 3072;   // 3*4H
constexpr int R3 = 384;    // 3*B (branch-major rows: r = k*B + b)
constexpr int NCAT = D2 + G3;  // 3584
constexpr float LAMDA = 3.0f;
constexpr float EPSF  = 1e-8f;

typedef __attribute__((ext_vector_type(8))) short bf16x8;
typedef __attribute__((ext_vector_type(8))) short short8;
typedef __attribute__((ext_vector_type(4))) float f32x4;

__device__ __forceinline__ ushort f2bf(float v) {
  uint u = __builtin_bit_cast(uint, v);
  u = (u + 0x7fffu + ((u >> 16) & 1u)) >> 16;   // RNE
  return (ushort)u;
}
__device__ __forceinline__ float bf2f(ushort h) {
  return __builtin_bit_cast(float, (uint)h << 16);
}
__device__ __forceinline__ float bflo(uint w) { return __builtin_bit_cast(float, w << 16); }
__device__ __forceinline__ float bfhi(uint w) { return __builtin_bit_cast(float, w & 0xffff0000u); }
__device__ __forceinline__ void split2(float v, ushort& h, ushort& l) {
  h = f2bf(v);
  l = f2bf(v - bf2f(h));
}

// ---------------- init: stack s1,s2,s3 into st3 (+ optional bf16 planes) ----------------
__global__ void k_init(const float* __restrict__ s1, const float* __restrict__ s2,
                       const float* __restrict__ s3, float* __restrict__ st3,
                       ushort* __restrict__ sth, ushort* __restrict__ stl) {
  int idx = blockIdx.x * blockDim.x + threadIdx.x;
  int total = R3 * D4;
  for (; idx < total; idx += gridDim.x * blockDim.x) {
    int r = idx / D4, i = idx - r * D4;
    int k = r / B, b = r - k * B;
    const float* s = (k == 0) ? s1 : (k == 1) ? s2 : s3;
    float v = s[b * D4 + i];
    st3[idx] = v;
    if (sth) { ushort h, l; split2(v, h, l); sth[idx] = h; stl[idx] = l; }
  }
}

// ---------------- conversions ----------------
__global__ void k_conv_m(const float* __restrict__ m, ushort* __restrict__ mbf) {
  int idx = blockIdx.x * blockDim.x + threadIdx.x;
  const int total8 = (B * L * D2) / 8;
  for (; idx < total8; idx += gridDim.x * blockDim.x) {
    const float4* p = reinterpret_cast<const float4*>(m) + (size_t)idx * 2;
    float4 a = p[0], c = p[1];
    ushort o[8] = {f2bf(a.x), f2bf(a.y), f2bf(a.z), f2bf(a.w),
                   f2bf(c.x), f2bf(c.y), f2bf(c.z), f2bf(c.w)};
    *reinterpret_cast<uint4*>(mbf + (size_t)idx * 8) = *reinterpret_cast<const uint4*>(o);
  }
}

// w2t[n][k] = bf16(w2[k][n])  (512x512) -- for mnorm
__global__ void k_w2t(const float* __restrict__ w2, ushort* __restrict__ w2t) {
  __shared__ ushort t[64][65];
  int bk = (blockIdx.x & 7) * 64, bn = (blockIdx.x >> 3) * 64;
  int tid = threadIdx.x;
#pragma unroll
  for (int i = 0; i < 16; ++i) {
    int e = tid + i * 256; int r = e >> 6, c = e & 63;
    t[r][c] = f2bf(w2[(bk + r) * 512 + bn + c]);
  }
  __syncthreads();
#pragma unroll
  for (int i = 0; i < 16; ++i) {
    int e = tid + i * 256; int r = e >> 6, c = e & 63;
    w2t[(bn + r) * 512 + bk + c] = t[c][r];
  }
}

// split f32 [n][k]-layout matrix into bf16 hi/lo planes (same layout)
__global__ void k_split_direct(const float* __restrict__ in, ushort* __restrict__ oh,
                               ushort* __restrict__ ol, int n4) {
  int idx = blockIdx.x * blockDim.x + threadIdx.x;
  for (; idx < n4; idx += gridDim.x * blockDim.x) {
    float4 v = reinterpret_cast<const float4*>(in)[idx];
    ushort4 h, l;
    split2(v.x, h.x, l.x); split2(v.y, h.y, l.y);
    split2(v.z, h.z, l.z); split2(v.w, h.w, l.w);
    reinterpret_cast<ushort4*>(oh)[idx] = h;
    reinterpret_cast<ushort4*>(ol)[idx] = l;
  }
}

// transpose-split: f32 in [K][N] -> hi/lo planes [N][K]
__global__ void k_split_trans(const float* __restrict__ in, int K, int N,
                              ushort* __restrict__ oh, ushort* __restrict__ ol) {
  __shared__ float t[64][65];
  int bk = blockIdx.x * 64, bn = blockIdx.y * 64;
  int tid = threadIdx.x;
#pragma unroll
  for (int i = 0; i < 16; ++i) {
    int e = tid + i * 256; int r = e >> 6, c = e & 63;
    t[r][c] = in[(size_t)(bk + r) * N + bn + c];
  }
  __syncthreads();
#pragma unroll
  for (int i = 0; i < 16; ++i) {
    int e = tid + i * 256; int r = e >> 6, c = e & 63;
    ushort h, l;
    split2(t[c][r], h, l);
    oh[(size_t)(bn + r) * K + bk + c] = h;
    ol[(size_t)(bn + r) * K + bk + c] = l;
  }
}

__global__ void k_bcat(const float* __restrict__ b3, const float* __restrict__ gbh,
                       float* __restrict__ bcat) {
  int idx = blockIdx.x * blockDim.x + threadIdx.x;
  if (idx < NCAT) bcat[idx] = (idx < D2) ? b3[idx] : gbh[idx - D2];
}

// ---------------- split-bf16 MFMA GEMM: C = act(A@B + bias) ----------------
// A given as hi/lo planes [M][K]; B as hi/lo planes [N][K]. 1 wave per block,
// 64x64 tile, 4x4 fragments of 16x16x32. acc = Ah@Bh + Al@Bh + Ah@Bl.
template <int ACT, bool SPLIT1>
__global__ __launch_bounds__(64) void k_gemm_sp(
    const ushort* __restrict__ Ahp, const ushort* __restrict__ Alp,
    const ushort* __restrict__ Bhp, const ushort* __restrict__ Blp,
    int Kd, const float* __restrict__ bias,
    float* __restrict__ C1f, ushort* __restrict__ C1h, ushort* __restrict__ C1l,
    int ldc1, int n1, float* __restrict__ C2, int ldc2) {
  const int ln = threadIdx.x;
  const int lrow = ln & 15, lk = ln >> 4;
  const int rowb = blockIdx.y * 64;
  const int colb = blockIdx.x * 64;
  size_t aoff[4], boff[4];
#pragma unroll
  for (int f = 0; f < 4; ++f) {
    aoff[f] = (size_t)(rowb + f * 16 + lrow) * Kd + lk * 8;
    boff[f] = (size_t)(colb + f * 16 + lrow) * Kd + lk * 8;
  }
  f32x4 acc[4][4] = {};
  for (int kc = 0; kc < Kd; kc += 32) {
    bf16x8 ah[4], al[4], bh[4], bl[4];
#pragma unroll
    for (int f = 0; f < 4; ++f) {
      ah[f] = *reinterpret_cast<const bf16x8*>(Ahp + aoff[f] + kc);
      al[f] = *reinterpret_cast<const bf16x8*>(Alp + aoff[f] + kc);
      bh[f] = *reinterpret_cast<const bf16x8*>(Bhp + boff[f] + kc);
      bl[f] = *reinterpret_cast<const bf16x8*>(Blp + boff[f] + kc);
    }
#pragma unroll
    for (int rf = 0; rf < 4; ++rf)
#pragma unroll
      for (int cf = 0; cf < 4; ++cf) {
        acc[rf][cf] = __builtin_amdgcn_mfma_f32_16x16x32_bf16(ah[rf], bh[cf], acc[rf][cf], 0, 0, 0);
        acc[rf][cf] = __builtin_amdgcn_mfma_f32_16x16x32_bf16(al[rf], bh[cf], acc[rf][cf], 0, 0, 0);
        acc[rf][cf] = __builtin_amdgcn_mfma_f32_16x16x32_bf16(ah[rf], bl[cf], acc[rf][cf], 0, 0, 0);
      }
  }
#pragma unroll
  for (int rf = 0; rf < 4; ++rf)
#pragma unroll
    for (int cf = 0; cf < 4; ++cf) {
      int col = colb + cf * 16 + lrow;
      float bb = bias ? bias[col] : 0.f;
#pragma unroll
      for (int j = 0; j < 4; ++j) {
        int row = rowb + rf * 16 + lk * 4 + j;
        float v = acc[rf][cf][j] + bb;
        if (ACT == 1) v = fmaxf(v, 0.f);
        if (col < n1) {
          if (SPLIT1) {
            ushort h, l; split2(v, h, l);
            C1h[(size_t)row * ldc1 + col] = h;
            C1l[(size_t)row * ldc1 + col] = l;
          } else {
            C1f[(size_t)row * ldc1 + col] = v;
          }
        } else {
          C2[(size_t)row * ldc2 + (col - n1)] = v;
        }
      }
    }
}

// ---------------- m_norm^2 via bf16 MFMA ----------------
__global__ __launch_bounds__(256) void k_mnorm_mfma(const ushort* __restrict__ mbf,
                                                    const ushort* __restrict__ w2t,
                                                    const float* __restrict__ b2,
                                                    float* __restrict__ norm2) {
  __shared__ ushort As[128][40];
  __shared__ ushort Bs[64][40];
  const int tid = threadIdx.x;
  const int wv = tid >> 6, ln = tid & 63;
  const int lrow = ln & 15, lk = ln >> 4;
  const long rowb = (long)blockIdx.x * 128;
  float nrm[2][4] = {};
  for (int ct = 0; ct < 8; ++ct) {
    f32x4 acc[2][4] = {};
    for (int kc = 0; kc < 512; kc += 32) {
      {
        int e = tid;
#pragma unroll
        for (int i = 0; i < 2; ++i, e += 256) {
          int r = e >> 2, s = e & 3;
          *reinterpret_cast<short8*>(&As[r][s * 8]) =
              *reinterpret_cast<const short8*>(&mbf[(size_t)(rowb + r) * 512 + kc + s * 8]);
        }
        int r = tid >> 2, s = tid & 3;
        *reinterpret_cast<short8*>(&Bs[r][s * 8]) =
            *reinterpret_cast<const short8*>(&w2t[(size_t)(ct * 64 + r) * 512 + kc + s * 8]);
      }
      __syncthreads();
      bf16x8 af[2], bfr[4];
#pragma unroll
      for (int rf = 0; rf < 2; ++rf)
        af[rf] = *reinterpret_cast<const bf16x8*>(&As[wv * 32 + rf * 16 + lrow][lk * 8]);
#pragma unroll
      for (int cf = 0; cf < 4; ++cf)
        bfr[cf] = *reinterpret_cast<const bf16x8*>(&Bs[cf * 16 + lrow][lk * 8]);
#pragma unroll
      for (int rf = 0; rf < 2; ++rf)
#pragma unroll
        for (int cf = 0; cf < 4; ++cf)
          acc[rf][cf] = __builtin_amdgcn_mfma_f32_16x16x32_bf16(af[rf], bfr[cf], acc[rf][cf], 0, 0, 0);
      __syncthreads();
    }
#pragma unroll
    for (int cf = 0; cf < 4; ++cf) {
      float bb = b2[ct * 64 + cf * 16 + lrow];
#pragma unroll
      for (int rf = 0; rf < 2; ++rf)
#pragma unroll
        for (int j = 0; j < 4; ++j) {
          float v = acc[rf][cf][j] + bb;
          nrm[rf][j] = fmaf(v, v, nrm[rf][j]);
        }
    }
  }
#pragma unroll
  for (int rf = 0; rf < 2; ++rf)
#pragma unroll
    for (int j = 0; j < 4; ++j) {
      float v = nrm[rf][j];
      v += __shfl_xor(v, 1); v += __shfl_xor(v, 2);
      v += __shfl_xor(v, 4); v += __shfl_xor(v, 8);
      nrm[rf][j] = v;
    }
  if (lrow == 0) {
#pragma unroll
    for (int rf = 0; rf < 2; ++rf)
#pragma unroll
      for (int j = 0; j < 4; ++j)
        norm2[rowb + wv * 32 + rf * 16 + lk * 4 + j] = nrm[rf][j];
  }
}

// ---------------- s_norm & c = w2_b . stt (from split planes) ----------------
__global__ void k_snorm_sp(const ushort* __restrict__ stth, const ushort* __restrict__ sttl,
                           const float* __restrict__ b2,
                           float* __restrict__ sn3, float* __restrict__ c3) {
  int r = blockIdx.x;
  int tid = threadIdx.x;
  float ss = 0.f, sc = 0.f;
  for (int j = tid; j < D2; j += 256) {
    float v = bf2f(stth[(size_t)r * D2 + j]) + bf2f(sttl[(size_t)r * D2 + j]);
    ss = fmaf(v, v, ss);
    sc = fmaf(v, b2[j], sc);
  }
  for (int o = 32; o; o >>= 1) {
    ss += __shfl_down(ss, o);
    sc += __shfl_down(sc, o);
  }
  __shared__ float rs[4], rc[4];
  int w = tid >> 6;
  if ((tid & 63) == 0) { rs[w] = ss; rc[w] = sc; }
  __syncthreads();
  if (tid == 0) {
    sn3[r] = fmaxf(sqrtf(rs[0] + rs[1] + rs[2] + rs[3]), EPSF);
    c3[r] = rc[0] + rc[1] + rc[2] + rc[3];
  }
}

// ---------------- dot pass (bf16 m) ----------------
__global__ __launch_bounds__(256) void k_dot_bf(const ushort* __restrict__ mbf,
                                                const float* __restrict__ shat3,
                                                const float* __restrict__ norm2,
                                                const float* __restrict__ sn3,
                                                const float* __restrict__ c3,
                                                const int* __restrict__ mask,
                                                float* __restrict__ att3) {
  __shared__ float sh[3][512];
  int b = blockIdx.x >> 3;
  int lt = blockIdx.x & 7;
  int tid = threadIdx.x;
  for (int k = 0; k < 3; ++k)
    for (int i = tid; i < 512; i += 256) sh[k][i] = shat3[(long)(k * B + b) * D2 + i];
  __syncthreads();
  int j = tid & 3, lidx = tid >> 2;
  int l = lt * 64 + lidx;
  const uint4* mrow = reinterpret_cast<const uint4*>(mbf + (size_t)(b * L + l) * D2);
  float a0 = 0.f, a1 = 0.f, a2 = 0.f;
#pragma unroll 4
  for (int s = 0; s < 16; ++s) {
    int c = s * 4 + j;
    uint4 mv = mrow[c];
    const float* p0 = &sh[0][c * 8];
    const float* p1 = &sh[1][c * 8];
    const float* p2 = &sh[2][c * 8];
    uint w[4] = {mv.x, mv.y, mv.z, mv.w};
#pragma unroll
    for (int q = 0; q < 4; ++q) {
      float lo = bflo(w[q]), hi = bfhi(w[q]);
      a0 = fmaf(lo, p0[q * 2], a0); a0 = fmaf(hi, p0[q * 2 + 1], a0);
      a1 = fmaf(lo, p1[q * 2], a1); a1 = fmaf(hi, p1[q * 2 + 1], a1);
      a2 = fmaf(lo, p2[q * 2], a2); a2 = fmaf(hi, p2[q * 2 + 1], a2);
    }
  }
  a0 += __shfl_xor(a0, 1); a0 += __shfl_xor(a0, 2);
  a1 += __shfl_xor(a1, 1); a1 += __shfl_xor(a1, 2);
  a2 += __shfl_xor(a2, 1); a2 += __shfl_xor(a2, 2);
  if (j == 0) {
    float mn = fmaxf(sqrtf(norm2[b * L + l]), EPSF);
    bool inv = (mask[b * L + l] == 0);
    float acc[3] = {a0, a1, a2};
#pragma unroll
    for (int k = 0; k < 3; ++k) {
      int r = k * B + b;
      float dot = acc[k] + c3[r];
      float att = LAMDA * dot / (mn * sn3[r]);
      att3[(long)r * L + l] = inv ? -INFINITY : att;
    }
  }
}

// ---------------- softmax over L per (k,b) row, in place ----------------
__global__ void k_softmax(float* __restrict__ att3) {
  int r = blockIdx.x;
  float* row = att3 + (long)r * L;
  int tid = threadIdx.x;
  float x0 = row[tid], x1 = row[tid + 256];
  float mx = fmaxf(x0, x1);
  for (int o = 32; o; o >>= 1) mx = fmaxf(mx, __shfl_xor(mx, o));
  __shared__ float rm[4], rs[4];
  int w = tid >> 6;
  if ((tid & 63) == 0) rm[w] = mx;
  __syncthreads();
  mx = fmaxf(fmaxf(rm[0], rm[1]), fmaxf(rm[2], rm[3]));
  float e0 = expf(x0 - mx), e1 = expf(x1 - mx);
  float s = e0 + e1;
  for (int o = 32; o; o >>= 1) s += __shfl_xor(s, o);
  if ((tid & 63) == 0) rs[w] = s;
  __syncthreads();
  s = rs[0] + rs[1] + rs[2] + rs[3];
  float inv = 1.0f / s;
  row[tid] = e0 * inv;
  row[tid + 256] = e1 * inv;
}

// ---------------- f_att = p @ m -> split planes ----------------
__global__ __launch_bounds__(256) void k_fatt_bf(const ushort* __restrict__ mbf,
                                                 const float* __restrict__ p3,
                                                 ushort* __restrict__ fatth,
                                                 ushort* __restrict__ fattl) {
  __shared__ float pp[3][512];
  __shared__ float red[3][256];
  int b = blockIdx.x >> 1, dt = blockIdx.x & 1;
  int tid = threadIdx.x;
  for (int k = 0; k < 3; ++k)
    for (int i = tid; i < 512; i += 256) pp[k][i] = p3[(long)(k * B + b) * L + i];
  __syncthreads();
  int dpair = tid & 127, half = tid >> 7;
  int d = dt * 256 + dpair * 2;
  float a[3][2] = {};
  int l0 = half * 256;
  for (int l = l0; l < l0 + 256; ++l) {
    uint w = *reinterpret_cast<const uint*>(&mbf[(size_t)(b * L + l) * D2 + d]);
    float f0 = bflo(w), f1 = bfhi(w);
#pragma unroll
    for (int k = 0; k < 3; ++k) {
      float p = pp[k][l];
      a[k][0] = fmaf(p, f0, a[k][0]);
      a[k][1] = fmaf(p, f1, a[k][1]);
    }
  }
  if (half == 1) {
#pragma unroll
    for (int k = 0; k < 3; ++k) { red[k][dpair * 2] = a[k][0]; red[k][dpair * 2 + 1] = a[k][1]; }
  }
  __syncthreads();
  if (half == 0) {
#pragma unroll
    for (int k = 0; k < 3; ++k) {
      float v0 = a[k][0] + red[k][dpair * 2];
      float v1 = a[k][1] + red[k][dpair * 2 + 1];
      ushort h0, l0u, h1, l1u;
      split2(v0, h0, l0u); split2(v1, h1, l1u);
      size_t o = (size_t)(k * B + b) * D2 + d;
      fatth[o] = h0; fattl[o] = l0u;
      fatth[o + 1] = h1; fattl[o + 1] = l1u;
    }
  }
}

// ---------------- GRU gates: st = (1-z)*n + z*st  (+ split planes) ----------------
__global__ void k_gates(const float* __restrict__ gx, const float* __restrict__ gh,
                        float* __restrict__ st3,
                        ushort* __restrict__ sth, ushort* __restrict__ stl) {
  int idx = blockIdx.x * blockDim.x + threadIdx.x;
  if (idx >= R3 * D4) return;
  int r = idx / D4, i = idx - r * D4;
  const float* gxr = gx + (long)r * G3;
  const float* ghr = gh + (long)r * G3;
  float xr = gxr[i], xz = gxr[D4 + i], xn = gxr[2 * D4 + i];
  float hr = ghr[i], hz = ghr[D4 + i], hn = ghr[2 * D4 + i];
  float rr = 1.f / (1.f + expf(-(xr + hr)));
  float zz = 1.f / (1.f + expf(-(xz + hz)));
  float nn = tanhf(xn + rr * hn);
  float h = st3[idx];
  float nv = (1.f - zz) * nn + zz * h;
  st3[idx] = nv;
  if (sth) { ushort hh, ll; split2(nv, hh, ll); sth[idx] = hh; stl[idx] = ll; }
}

// ---------------- o3[r] = h4[r] . w5 + b5 ----------------
__global__ void k_w5(const float* __restrict__ h4, const float* __restrict__ w5w,
                     const float* __restrict__ w5b, float* __restrict__ o3) {
  int r = blockIdx.x, tid = threadIdx.x;
  float s = 0.f;
  for (int d = tid; d < D4; d += 256) s = fmaf(h4[(long)r * D4 + d], w5w[d], s);
  for (int o = 32; o; o >>= 1) s += __shfl_down(s, o);
  __shared__ float rs[4];
  if ((tid & 63) == 0) rs[tid >> 6] = s;
  __syncthreads();
  if (tid == 0) o3[r] = rs[0] + rs[1] + rs[2] + rs[3] + w5b[0];
}

// ---------------- final log_softmax over 3 branches ----------------
__global__ void k_final(const float* __restrict__ o3, float* __restrict__ out) {
  int b = threadIdx.x;
  if (b >= B) return;
  float v0 = o3[0 * B + b], v1 = o3[1 * B + b], v2 = o3[2 * B + b];
  float mx = fmaxf(v0, fmaxf(v1, v2));
  float s = expf(v0 - mx) + expf(v1 - mx) + expf(v2 - mx);
  float lse = mx + logf(s);
  out[b * 3 + 0] = v0 - lse;
  out[b * 3 + 1] = v1 - lse;
  out[b * 3 + 2] = v2 - lse;
}

// ================= fallback f32 kernels (small-ws path, as R2) =================
__global__ __launch_bounds__(256) void k_mnorm(const float* __restrict__ m,
                                               const float* __restrict__ w2,
                                               const float* __restrict__ b2,
                                               float* __restrict__ norm2) {
  __shared__ float As[64][33];
  __shared__ float Ws[32][65];
  __shared__ float red[16][64];
  const int tid = threadIdx.x;
  const int ty = tid >> 4, tx = tid & 15;
  const long rowb = (long)blockIdx.x * 64;
  float rowpart[4] = {0.f, 0.f, 0.f, 0.f};
  for (int ct = 0; ct < 8; ++ct) {
    float acc[4][4] = {};
    for (int kc = 0; kc < 16; ++kc) {
#pragma unroll
      for (int i = 0; i < 8; ++i) {
        int li = tid + i * 256;
        int r = li >> 5, c = li & 31;
        As[r][c] = m[(rowb + r) * 512 + kc * 32 + c];
      }
#pragma unroll
      for (int i = 0; i < 8; ++i) {
        int li = tid + i * 256;
        int r = li >> 6, c = li & 63;
        Ws[r][c] = w2[(kc * 32 + r) * 512 + ct * 64 + c];
      }
      __syncthreads();
#pragma unroll
      for (int k = 0; k < 32; ++k) {
        float a[4], bb[4];
#pragma unroll
        for (int i = 0; i < 4; ++i) a[i] = As[ty * 4 + i][k];
#pragma unroll
        for (int j = 0; j < 4; ++j) bb[j] = Ws[k][tx * 4 + j];
#pragma unroll
        for (int i = 0; i < 4; ++i)
#pragma unroll
          for (int j = 0; j < 4; ++j) acc[i][j] = fmaf(a[i], bb[j], acc[i][j]);
      }
      __syncthreads();
    }
#pragma unroll
    for (int j = 0; j < 4; ++j) {
      float bj = b2[ct * 64 + tx * 4 + j];
#pragma unroll
      for (int i = 0; i < 4; ++i) {
        float v = acc[i][j] + bj;
        rowpart[i] = fmaf(v, v, rowpart[i]);
      }
    }
  }
#pragma unroll
  for (int i = 0; i < 4; ++i) red[tx][ty * 4 + i] = rowpart[i];
  __syncthreads();
  if (tid < 64) {
    float s = 0.f;
#pragma unroll
    for (int t = 0; t < 16; ++t) s += red[t][tid];
    norm2[rowb + tid] = s;
  }
}

template <bool BT, int ACT>
__global__ __launch_bounds__(256) void k_gemm64(const float* __restrict__ A, int lda,
                                                const float* __restrict__ Bm, int ldb,
                                                const float* __restrict__ bias,
                                                float* __restrict__ C, int ldc, int Kd) {
  __shared__ float As[64][33];
  __shared__ float Bs[32][65];
  const int tid = threadIdx.x;
  const int ty = tid >> 4, tx = tid & 15;
  const int rowb = blockIdx.y * 64;
  const int colb = blockIdx.x * 64;
  float acc[4][4] = {};
  for (int kc = 0; kc < Kd; kc += 32) {
#pragma unroll
    for (int i = 0; i < 8; ++i) {
      int li = tid + i * 256;
      int r = li >> 5, c = li & 31;
      As[r][c] = A[(long)(rowb + r) * lda + kc + c];
    }
    if (!BT) {
#pragma unroll
      for (int i = 0; i < 8; ++i) {
        int li = tid + i * 256;
        int r = li >> 6, c = li & 63;
        Bs[r][c] = Bm[(long)(kc + r) * ldb + colb + c];
      }
    } else {
#pragma unroll
      for (int i = 0; i < 8; ++i) {
        int li = tid + i * 256;
        int n = li >> 5, k = li & 31;
        Bs[k][n] = Bm[(long)(colb + n) * ldb + kc + k];
      }
    }
    __syncthreads();
#pragma unroll
    for (int k = 0; k < 32; ++k) {
      float a[4], bb[4];
#pragma unroll
      for (int i = 0; i < 4; ++i) a[i] = As[ty * 4 + i][k];
#pragma unroll
      for (int j = 0; j < 4; ++j) bb[j] = Bs[k][tx * 4 + j];
#pragma unroll
      for (int i = 0; i < 4; ++i)
#pragma unroll
        for (int j = 0; j < 4; ++j) acc[i][j] = fmaf(a[i], bb[j], acc[i][j]);
    }
    __syncthreads();
  }
#pragma unroll
  for (int i = 0; i < 4; ++i) {
    int row = rowb + ty * 4 + i;
#pragma unroll
    for (int j = 0; j < 4; ++j) {
      int col = colb + tx * 4 + j;
      float v = acc[i][j];
      if (bias) v += bias[col];
      if (ACT == 1) v = fmaxf(v, 0.f);
      C[(long)row * ldc + col] = v;
    }
  }
}

__global__ void k_snorm(const float* __restrict__ stt3, const float* __restrict__ b2,
                        float* __restrict__ sn3, float* __restrict__ c3) {
  int r = blockIdx.x;
  int tid = threadIdx.x;
  float ss = 0.f, sc = 0.f;
  for (int j = tid; j < D2; j += 256) {
    float v = stt3[(long)r * D2 + j];
    ss = fmaf(v, v, ss);
    sc = fmaf(v, b2[j], sc);
  }
  for (int o = 32; o; o >>= 1) {
    ss += __shfl_down(ss, o);
    sc += __shfl_down(sc, o);
  }
  __shared__ float rs[4], rc[4];
  int w = tid >> 6;
  if ((tid & 63) == 0) { rs[w] = ss; rc[w] = sc; }
  __syncthreads();
  if (tid == 0) {
    sn3[r] = fmaxf(sqrtf(rs[0] + rs[1] + rs[2] + rs[3]), EPSF);
    c3[r] = rc[0] + rc[1] + rc[2] + rc[3];
  }
}

__global__ __launch_bounds__(256) void k_dot(const float* __restrict__ m,
                                             const float* __restrict__ shat3,
                                             const float* __restrict__ norm2,
                                             const float* __restrict__ sn3,
                                             const float* __restrict__ c3,
                                             const int* __restrict__ mask,
                                             float* __restrict__ att3) {
  __shared__ float sh[3][512];
  int b = blockIdx.x >> 3;
  int lt = blockIdx.x & 7;
  int tid = threadIdx.x;
  for (int k = 0; k < 3; ++k)
    for (int i = tid; i < 512; i += 256) sh[k][i] = shat3[(long)(k * B + b) * D2 + i];
  __syncthreads();
  int j = tid & 3, lidx = tid >> 2;
  int l = lt * 64 + lidx;
  const float4* mrow = reinterpret_cast<const float4*>(m + (long)(b * L + l) * D2);
  float a0 = 0.f, a1 = 0.f, a2 = 0.f;
#pragma unroll 8
  for (int s = 0; s < 32; ++s) {
    int d4 = s * 4 + j;
    float4 mv = mrow[d4];
    const float4 v0 = *reinterpret_cast<const float4*>(&sh[0][d4 * 4]);
    const float4 v1 = *reinterpret_cast<const float4*>(&sh[1][d4 * 4]);
    const float4 v2 = *reinterpret_cast<const float4*>(&sh[2][d4 * 4]);
    a0 += mv.x * v0.x + mv.y * v0.y + mv.z * v0.z + mv.w * v0.w;
    a1 += mv.x * v1.x + mv.y * v1.y + mv.z * v1.z + mv.w * v1.w;
    a2 += mv.x * v2.x + mv.y * v2.y + mv.z * v2.z + mv.w * v2.w;
  }
  a0 += __shfl_xor(a0, 1); a0 += __shfl_xor(a0, 2);
  a1 += __shfl_xor(a1, 1); a1 += __shfl_xor(a1, 2);
  a2 += __shfl_xor(a2, 1); a2 += __shfl_xor(a2, 2);
  if (j == 0) {
    float mn = fmaxf(sqrtf(norm2[b * L + l]), EPSF);
    bool inv = (mask[b * L + l] == 0);
    float acc[3] = {a0, a1, a2};
#pragma unroll
    for (int k = 0; k < 3; ++k) {
      int r = k * B + b;
      float dot = acc[k] + c3[r];
      float att = LAMDA * dot / (mn * sn3[r]);
      att3[(long)r * L + l] = inv ? -INFINITY : att;
    }
  }
}

__global__ __launch_bounds__(256) void k_fatt(const float* __restrict__ m,
                                              const float* __restrict__ p3,
                                              float* __restrict__ fatt3) {
  __shared__ float pp[3][512];
  __shared__ float red[3][128];
  int b = blockIdx.x >> 2, dt = blockIdx.x & 3;
  int tid = threadIdx.x;
  for (int k = 0; k < 3; ++k)
    for (int i = tid; i < 512; i += 256) pp[k][i] = p3[(long)(k * B + b) * L + i];
  __syncthreads();
  int d = dt * 128 + (tid & 127);
  int half = tid >> 7;
  float a0 = 0.f, a1 = 0.f, a2 = 0.f;
  int l0 = half * 256;
  for (int l = l0; l < l0 + 256; ++l) {
    float mv = m[(long)(b * L + l) * D2 + d];
    a0 = fmaf(pp[0][l], mv, a0);
    a1 = fmaf(pp[1][l], mv, a1);
    a2 = fmaf(pp[2][l], mv, a2);
  }
  int dd = tid & 127;
  if (half == 1) { red[0][dd] = a0; red[1][dd] = a1; red[2][dd] = a2; }
  __syncthreads();
  if (half == 0) {
    fatt3[(long)(0 * B + b) * D2 + d] = a0 + red[0][dd];
    fatt3[(long)(1 * B + b) * D2 + d] = a1 + red[1][dd];
    fatt3[(long)(2 * B + b) * D2 + d] = a2 + red[2][dd];
  }
}

extern "C" void kernel_launch(void* const* d_in, const int* in_sizes, int n_in,
                              void* d_out, int out_size, void* d_ws, size_t ws_size,
                              hipStream_t stream) {
  const float* m    = (const float*)d_in[0];
  const float* s1   = (const float*)d_in[1];
  const float* s2   = (const float*)d_in[2];
  const float* s3   = (const float*)d_in[3];
  const int*   mask = (const int*)d_in[4];
  const float* w2w  = (const float*)d_in[5];
  const float* w2b  = (const float*)d_in[6];
  const float* w3w  = (const float*)d_in[7];
  const float* w3b  = (const float*)d_in[8];
  const float* w4w  = (const float*)d_in[9];
  const float* w4b  = (const float*)d_in[10];
  const float* w5w  = (const float*)d_in[11];
  const float* w5b  = (const float*)d_in[12];
  const float* gwi  = (const float*)d_in[13];
  const float* gwh  = (const float*)d_in[14];
  const float* gbi  = (const float*)d_in[15];
  const float* gbh  = (const float*)d_in[16];
  float* out = (float*)d_out;

  float* ws = (float*)d_ws;
  size_t off = 0;
  auto alloc = [&](size_t n) {
    float* p = ws + off;
    off += (n + 63) & ~(size_t)63;
    return p;
  };
  // ---- big-path layout ----
  ushort* mbf   = (ushort*)alloc((size_t)B * L * D2 / 2);
  ushort* w2t   = (ushort*)alloc((size_t)D2 * D2 / 2);
  ushort* catBh = (ushort*)alloc((size_t)NCAT * D4 / 2);
  ushort* catBl = (ushort*)alloc((size_t)NCAT * D4 / 2);
  ushort* gxBh  = (ushort*)alloc((size_t)G3 * D2 / 2);
  ushort* gxBl  = (ushort*)alloc((size_t)G3 * D2 / 2);
  ushort* w4Bh  = (ushort*)alloc((size_t)D4 * D4 / 2);
  ushort* w4Bl  = (ushort*)alloc((size_t)D4 * D4 / 2);
  ushort* shBh  = (ushort*)alloc((size_t)D2 * D2 / 2);
  ushort* shBl  = (ushort*)alloc((size_t)D2 * D2 / 2);
  float* bcat   = alloc(NCAT);
  float* norm2  = alloc((size_t)B * L);
  float* st3    = alloc((size_t)R3 * D4);
  ushort* sth   = (ushort*)alloc((size_t)R3 * D4 / 2);
  ushort* stl   = (ushort*)alloc((size_t)R3 * D4 / 2);
  ushort* stth  = (ushort*)alloc((size_t)R3 * D2 / 2);
  ushort* sttl  = (ushort*)alloc((size_t)R3 * D2 / 2);
  float* shat3  = alloc((size_t)R3 * D2);
  float* sn3    = alloc(R3);
  float* c3     = alloc(R3);
  float* att3   = alloc((size_t)3 * B * L);
  ushort* fatth = (ushort*)alloc((size_t)R3 * D2 / 2);
  ushort* fattl = (ushort*)alloc((size_t)R3 * D2 / 2);
  float* gx     = alloc((size_t)R3 * G3);
  float* gh     = alloc((size_t)R3 * G3);
  float* h4     = alloc((size_t)R3 * D4);
  float* o3     = alloc(R3);
  const bool big = ws_size >= off * sizeof(float);

  if (big) {
    // ---- one-time conversions ----
    k_init<<<256, 256, 0, stream>>>(s1, s2, s3, st3, sth, stl);
    k_conv_m<<<2048, 256, 0, stream>>>(m, mbf);
    k_w2t<<<64, 256, 0, stream>>>(w2w, w2t);
    k_mnorm_mfma<<<(B * L) / 128, 256, 0, stream>>>(mbf, w2t, w2b, norm2);
    k_bcat<<<(NCAT + 255) / 256, 256, 0, stream>>>(w3b, gbh, bcat);
    // catB rows [0,512) = w3_w^T ; rows [512,3584) = gwh (already [n][k])
    k_split_trans<<<dim3(D4 / 64, D2 / 64), 256, 0, stream>>>(w3w, D4, D2, catBh, catBl);
    k_split_direct<<<1024, 256, 0, stream>>>(gwh, catBh + (size_t)D2 * D4, catBl + (size_t)D2 * D4,
                                             (G3 * D4) / 4);
    k_split_direct<<<1024, 256, 0, stream>>>(gwi, gxBh, gxBl, (G3 * D2) / 4);
    k_split_trans<<<dim3(D4 / 64, D4 / 64), 256, 0, stream>>>(w4w, D4, D4, w4Bh, w4Bl);
    k_split_direct<<<1024, 256, 0, stream>>>(w2w, shBh, shBl, (D2 * D2) / 4);

    for (int hop = 0; hop < 3; ++hop) {
      // [stt | gh] = st @ [w3 | gwh^T] + [b3 | bh]
      k_gemm_sp<0, true><<<dim3(NCAT / 64, R3 / 64), 64, 0, stream>>>(
          sth, stl, catBh, catBl, D4, bcat, nullptr, stth, sttl, D2, D2, gh, G3);
      k_snorm_sp<<<R3, 256, 0, stream>>>(stth, sttl, w2b, sn3, c3);
      // shat = stt @ w2^T
      k_gemm_sp<0, false><<<dim3(D2 / 64, R3 / 64), 64, 0, stream>>>(
          stth, sttl, shBh, shBl, D2, nullptr, shat3, nullptr, nullptr, D2, D2, shat3, D2);
      k_dot_bf<<<B * 8, 256, 0, stream>>>(mbf, shat3, norm2, sn3, c3, mask, att3);
      k_softmax<<<3 * B, 256, 0, stream>>>(att3);
      k_fatt_bf<<<B * 2, 256, 0, stream>>>(mbf, att3, fatth, fattl);
      // gx = f_att @ wi^T + bi
      k_gemm_sp<0, false><<<dim3(G3 / 64, R3 / 64), 64, 0, stream>>>(
          fatth, fattl, gxBh, gxBl, D2, gbi, gx, nullptr, nullptr, G3, G3, gx, G3);
      k_gates<<<(R3 * D4) / 256, 256, 0, stream>>>(gx, gh, st3, sth, stl);
    }
    // h = relu(st @ w4 + b4)
    k_gemm_sp<1, false><<<dim3(D4 / 64, R3 / 64), 64, 0, stream>>>(
        sth, stl, w4Bh, w4Bl, D4, w4b, h4, nullptr, nullptr, D4, D4, h4, D4);
  } else {
    // ---- f32 fallback (R2 small path) ----
    float* stt3  = shat3;  // reuse: fallback needs f32 stt; shat written later? no -> alloc区 reuse is unsafe; use gx region start
    stt3 = gx;             // gx (1.18M floats) unused until after shat in this path order; but shat gemm reads stt3 -> ok, gx written after
    float* fatt3 = gh + (size_t)R3 * G3 - (size_t)R3 * D2;  // tail of gh region, unused before gx gemm reads fatt3? gh written same hop...
    fatt3 = h4;            // h4 unused until final; safe scratch for fatt f32
    k_init<<<256, 256, 0, stream>>>(s1, s2, s3, st3, nullptr, nullptr);
    k_mnorm<<<(B * L) / 64, 256, 0, stream>>>(m, w2w, w2b, norm2);
    for (int hop = 0; hop < 3; ++hop) {
      k_gemm64<false, 0><<<dim3(D2 / 64, R3 / 64), 256, 0, stream>>>(st3, D4, w3w, D2, w3b, stt3, D2, D4);
      k_snorm<<<R3, 256, 0, stream>>>(stt3, w2b, sn3, c3);
      k_gemm64<true, 0><<<dim3(D2 / 64, R3 / 64), 256, 0, stream>>>(stt3, D2, w2w, D2, nullptr, shat3, D2, D2);
      k_dot<<<B * 8, 256, 0, stream>>>(m, shat3, norm2, sn3, c3, mask, att3);
      k_softmax<<<3 * B, 256, 0, stream>>>(att3);
      k_fatt<<<B * 4, 256, 0, stream>>>(m, att3, fatt3);
      k_gemm64<true, 0><<<dim3(G3 / 64, R3 / 64), 256, 0, stream>>>(fatt3, D2, gwi, D2, gbi, gx, G3, D2);
      k_gemm64<true, 0><<<dim3(G3 / 64, R3 / 64), 256, 0, stream>>>(st3, D4, gwh, D4, gbh, gh, G3, D4);
      k_gates<<<(R3 * D4) / 256, 256, 0, stream>>>(gx, gh, st3, nullptr, nullptr);
    }
    k_gemm64<false, 1><<<dim3(D4 / 64, R3 / 64), 256, 0, stream>>>(st3, D4, w4w, D4, w4b, h4, D4, D4);
  }
  k_w5<<<R3, 256, 0, stream>>>(h4, w5w, w5b, o3);
  k_final<<<1, 128, 0, stream>>>(o3, out);
}